// Round 3
// baseline (226.769 us; speedup 1.0000x reference)
//
#include <hip/hip_runtime.h>
#include <float.h>
#include <stdint.h>

#define EMB_DIM  300
#define MAX_LEN  128
#define HIDDEN   1000
#define NCLS     5
#define VOCAB_SZ 50000
#define KPAD     640     // 600 padded to 20*32
#define NPAD     1024    // 1000 padded to 16*64

typedef float    f32x4  __attribute__((ext_vector_type(4)));
typedef __bf16   bf16x8 __attribute__((ext_vector_type(8)));

__device__ __forceinline__ unsigned short f2bf(float f) {
    union { float f; uint32_t u; } v; v.f = f;
    uint32_t u = v.u;
    return (unsigned short)((u + 0x7FFFu + ((u >> 16) & 1u)) >> 16);   // RNE
}

// ---------------------------------------------------------------------------
// init_out: out[b][c] = b2[c]  (gemm1 atomically accumulates on top)
// ---------------------------------------------------------------------------
__global__ __launch_bounds__(256) void init_out(
    float* __restrict__ out, const float* __restrict__ b2, int n)
{
    int i = blockIdx.x * 256 + threadIdx.x;
    if (i < n) out[i] = b2[i % NCLS];
}

// ---------------------------------------------------------------------------
// transpose+convert W1 [600][1000] f32 -> W1T [1024][640] bf16 (zero-padded)
// ---------------------------------------------------------------------------
__global__ __launch_bounds__(256) void transpose_w1(
    const float* __restrict__ W1, unsigned short* __restrict__ Bt)
{
    __shared__ float t[32][33];
    const int tx = threadIdx.x & 31, ty = threadIdx.x >> 5;   // 32 x 8
    const int n0 = blockIdx.x * 32, k0 = blockIdx.y * 32;
    #pragma unroll
    for (int i = 0; i < 4; ++i) {
        int k = k0 + ty + i * 8, n = n0 + tx;
        t[ty + i * 8][tx] = (k < 600 && n < HIDDEN) ? W1[(size_t)k * HIDDEN + n] : 0.f;
    }
    __syncthreads();
    #pragma unroll
    for (int i = 0; i < 4; ++i) {
        int n = n0 + ty + i * 8, k = k0 + tx;
        Bt[(size_t)n * KPAD + k] = f2bf(t[tx][ty + i * 8]);
    }
}

// ---------------------------------------------------------------------------
// pool v2: gather + masked avg/max pool -> rep bf16 [B][640].
// Block (75,4): tx owns 4 dims (float4), ty-group g handles tokens g, g+4, ...
// Serial chain per group ~L/4 iters, unrolled x2 (2 loads in flight/iter).
// Partials combined across the 4 groups via LDS.
// ---------------------------------------------------------------------------
__global__ __launch_bounds__(300) void pool_kernel(
    const int* __restrict__ x, const int* __restrict__ lengths,
    const float* __restrict__ emb, unsigned short* __restrict__ rep)
{
    const int b  = blockIdx.x;
    const int tx = threadIdx.x;          // 0..74
    const int ty = threadIdx.y;          // 0..3

    __shared__ int   sidx[MAX_LEN];
    __shared__ float psum[3][EMB_DIM];
    __shared__ float pmax[3][EMB_DIM];

    const int lin = ty * 75 + tx;
    if (lin < MAX_LEN) sidx[lin] = x[b * MAX_LEN + lin];
    __syncthreads();

    int L = lengths[b];
    L = max(1, min(L, MAX_LEN));

    const int d = tx * 4;
    float4 s  = {0.f, 0.f, 0.f, 0.f};
    float4 mx = {-FLT_MAX, -FLT_MAX, -FLT_MAX, -FLT_MAX};

    int i = ty;
    for (; i + 4 < L; i += 8) {
        int i0 = max(0, min(sidx[i],     VOCAB_SZ - 1));
        int i1 = max(0, min(sidx[i + 4], VOCAB_SZ - 1));
        const float4 v0 = *(const float4*)(emb + (size_t)i0 * EMB_DIM + d);
        const float4 v1 = *(const float4*)(emb + (size_t)i1 * EMB_DIM + d);
        s.x += v0.x; s.y += v0.y; s.z += v0.z; s.w += v0.w;
        mx.x = fmaxf(mx.x, v0.x); mx.y = fmaxf(mx.y, v0.y);
        mx.z = fmaxf(mx.z, v0.z); mx.w = fmaxf(mx.w, v0.w);
        s.x += v1.x; s.y += v1.y; s.z += v1.z; s.w += v1.w;
        mx.x = fmaxf(mx.x, v1.x); mx.y = fmaxf(mx.y, v1.y);
        mx.z = fmaxf(mx.z, v1.z); mx.w = fmaxf(mx.w, v1.w);
    }
    if (i < L) {
        int i0 = max(0, min(sidx[i], VOCAB_SZ - 1));
        const float4 v0 = *(const float4*)(emb + (size_t)i0 * EMB_DIM + d);
        s.x += v0.x; s.y += v0.y; s.z += v0.z; s.w += v0.w;
        mx.x = fmaxf(mx.x, v0.x); mx.y = fmaxf(mx.y, v0.y);
        mx.z = fmaxf(mx.z, v0.z); mx.w = fmaxf(mx.w, v0.w);
    }

    if (ty > 0) {
        *(float4*)&psum[ty - 1][d] = s;
        *(float4*)&pmax[ty - 1][d] = mx;
    }
    __syncthreads();

    unsigned short* rb = rep + (size_t)b * KPAD;

    if (ty == 0) {
        #pragma unroll
        for (int g = 0; g < 3; ++g) {
            float4 ps = *(const float4*)&psum[g][d];
            float4 pm = *(const float4*)&pmax[g][d];
            s.x += ps.x; s.y += ps.y; s.z += ps.z; s.w += ps.w;
            mx.x = fmaxf(mx.x, pm.x); mx.y = fmaxf(mx.y, pm.y);
            mx.z = fmaxf(mx.z, pm.z); mx.w = fmaxf(mx.w, pm.w);
        }
        const float inv = 1.0f / (float)L;
        ushort4 av, mv;
        av.x = f2bf(s.x * inv); av.y = f2bf(s.y * inv);
        av.z = f2bf(s.z * inv); av.w = f2bf(s.w * inv);
        mv.x = f2bf(mx.x); mv.y = f2bf(mx.y);
        mv.z = f2bf(mx.z); mv.w = f2bf(mx.w);
        *(ushort4*)(rb + d)       = av;    // avg -> [0,300)
        *(ushort4*)(rb + 300 + d) = mv;    // max -> [300,600)
    }
    if (ty == 1 && tx < 10) {              // zero pad [600,640)
        ushort4 z = {0, 0, 0, 0};
        *(ushort4*)(rb + 600 + tx * 4) = z;
    }
}

// ---------------------------------------------------------------------------
// gemm1_fused: logits += relu(rep @ W1 + b1) @ W2, atomically into out.
// Tile 128(M) x 64(N), BK=32, 4 waves (2x2), wave tile 64x32, dbuf LDS via
// global_load_lds(16B). Epilogue dots h with W2 and shfl-reduces over the
// 16-lane column groups, then 1 atomicAdd per (m,c) per wave.
// ---------------------------------------------------------------------------
#define BM 128
#define BN 64
#define BK 32

__global__ __launch_bounds__(256, 2) void gemm1_fused(
    const unsigned short* __restrict__ A,    // rep  [M][640] bf16
    const unsigned short* __restrict__ Bt,   // W1T  [1024][640] bf16
    const float* __restrict__ bias,          // b1 [1000]
    const float* __restrict__ W2,            // [1000][5]
    float* __restrict__ out,                 // [M][5], pre-init to b2
    int M)
{
    __shared__ unsigned short As[2][BM * BK];
    __shared__ unsigned short Bs[2][BN * BK];

    const int tid  = threadIdx.x;
    const int wv   = tid >> 6;
    const int lane = tid & 63;
    const int bm   = blockIdx.y * BM;
    const int bn   = blockIdx.x * BN;
    const int wr   = (wv & 1) * 64;
    const int wc   = (wv >> 1) * 32;

    f32x4 acc[4][2] = {};

    auto stage = [&](int buf, int k0) {
        #pragma unroll
        for (int j = 0; j < 2; ++j) {
            int ci  = (wv * 2 + j) * 64 + lane;
            int row = ci >> 2, c = ci & 3;
            const unsigned short* g = A + (size_t)(bm + row) * KPAD + k0 + c * 8;
            unsigned short* l = &As[buf][(wv * 2 + j) * 512];
            __builtin_amdgcn_global_load_lds(g, l, 16, 0, 0);
        }
        {
            int ci  = wv * 64 + lane;
            int row = ci >> 2, c = ci & 3;
            const unsigned short* g = Bt + (size_t)(bn + row) * KPAD + k0 + c * 8;
            unsigned short* l = &Bs[buf][wv * 512];
            __builtin_amdgcn_global_load_lds(g, l, 16, 0, 0);
        }
    };

    stage(0, 0);
    int cur = 0;
    const int q = lane >> 4, r16 = lane & 15;

    for (int it = 0; it < KPAD / BK; ++it) {
        __syncthreads();
        if (it + 1 < KPAD / BK) stage(cur ^ 1, (it + 1) * BK);

        bf16x8 af[4], bfr[2];
        #pragma unroll
        for (int mi = 0; mi < 4; ++mi)
            af[mi] = *(const bf16x8*)&As[cur][(wr + mi * 16 + r16) * BK + q * 8];
        #pragma unroll
        for (int nj = 0; nj < 2; ++nj)
            bfr[nj] = *(const bf16x8*)&Bs[cur][(wc + nj * 16 + r16) * BK + q * 8];
        #pragma unroll
        for (int mi = 0; mi < 4; ++mi)
            #pragma unroll
            for (int nj = 0; nj < 2; ++nj)
                acc[mi][nj] = __builtin_amdgcn_mfma_f32_16x16x32_bf16(
                    af[mi], bfr[nj], acc[mi][nj], 0, 0, 0);
        cur ^= 1;
    }

    // Epilogue: h = relu(acc + b1), p = h @ W2, reduce over r16, atomicAdd.
    float bv[2];
    float w2v[2][NCLS];
    #pragma unroll
    for (int nj = 0; nj < 2; ++nj) {
        int n = bn + wc + nj * 16 + r16;
        if (n < HIDDEN) {
            bv[nj] = bias[n];
            #pragma unroll
            for (int c = 0; c < NCLS; ++c) w2v[nj][c] = W2[(size_t)n * NCLS + c];
        } else {
            bv[nj] = 0.f;
            #pragma unroll
            for (int c = 0; c < NCLS; ++c) w2v[nj][c] = 0.f;
        }
    }

    #pragma unroll
    for (int mi = 0; mi < 4; ++mi) {
        #pragma unroll
        for (int r = 0; r < 4; ++r) {
            float p[NCLS] = {0.f, 0.f, 0.f, 0.f, 0.f};
            #pragma unroll
            for (int nj = 0; nj < 2; ++nj) {
                float h = fmaxf(acc[mi][nj][r] + bv[nj], 0.f);
                #pragma unroll
                for (int c = 0; c < NCLS; ++c) p[c] += h * w2v[nj][c];
            }
            #pragma unroll
            for (int off = 1; off < 16; off <<= 1)
                #pragma unroll
                for (int c = 0; c < NCLS; ++c)
                    p[c] += __shfl_xor(p[c], off, 64);
            if (r16 == 0) {
                int m = bm + wr + mi * 16 + q * 4 + r;
                #pragma unroll
                for (int c = 0; c < NCLS; ++c)
                    atomicAdd(&out[(size_t)m * NCLS + c], p[c]);
            }
        }
    }
}

// ---------------------------------------------------------------------------
extern "C" void kernel_launch(void* const* d_in, const int* in_sizes, int n_in,
                              void* d_out, int out_size, void* d_ws, size_t ws_size,
                              hipStream_t stream)
{
    const int*   x       = (const int*)d_in[0];
    const int*   lengths = (const int*)d_in[1];
    const float* emb     = (const float*)d_in[2];
    const float* W1      = (const float*)d_in[3];
    const float* b1      = (const float*)d_in[4];
    const float* W2      = (const float*)d_in[5];
    const float* b2      = (const float*)d_in[6];
    float*       out     = (float*)d_out;

    const int B = in_sizes[1];               // 4096

    unsigned short* rep = (unsigned short*)d_ws;          // [B][640]
    unsigned short* w1t = rep + (size_t)B * KPAD;         // [1024][640]

    init_out<<<(B * NCLS + 255) / 256, 256, 0, stream>>>(out, b2, B * NCLS);
    transpose_w1<<<dim3(32, 20), 256, 0, stream>>>(W1, w1t);
    pool_kernel<<<B, dim3(75, 4), 0, stream>>>(x, lengths, emb, rep);

    dim3 g1(NPAD / BN, B / BM);              // (16, 32)
    gemm1_fused<<<g1, 256, 0, stream>>>(rep, w1t, b1, W2, out, B);
}

// Round 5
// 167.118 us; speedup vs baseline: 1.3569x; 1.3569x over previous
//
#include <hip/hip_runtime.h>
#include <float.h>
#include <stdint.h>

#define EMB_DIM  300
#define MAX_LEN  128
#define HIDDEN   1000
#define NCLS     5
#define VOCAB_SZ 50000
#define KPAD     640     // 600 padded to 20*32
#define NPAD     1024    // 1000 padded to 16*64

typedef float    f32x4  __attribute__((ext_vector_type(4)));
typedef __bf16   bf16x8 __attribute__((ext_vector_type(8)));
typedef unsigned short ushort8v __attribute__((ext_vector_type(8)));

__device__ __forceinline__ unsigned short f2bf(float f) {
    union { float f; uint32_t u; } v; v.f = f;
    uint32_t u = v.u;
    return (unsigned short)((u + 0x7FFFu + ((u >> 16) & 1u)) >> 16);   // RNE
}
__device__ __forceinline__ float bf2f(unsigned short h) {
    union { uint32_t u; float f; } v; v.u = ((uint32_t)h) << 16;
    return v.f;
}

// ---------------------------------------------------------------------------
// transpose+convert W1 [600][1000] f32 -> W1T [1024][640] bf16 (zero-padded)
// ---------------------------------------------------------------------------
__global__ __launch_bounds__(256) void transpose_w1(
    const float* __restrict__ W1, unsigned short* __restrict__ Bt)
{
    __shared__ float t[32][33];
    const int tx = threadIdx.x & 31, ty = threadIdx.x >> 5;   // 32 x 8
    const int n0 = blockIdx.x * 32, k0 = blockIdx.y * 32;
    #pragma unroll
    for (int i = 0; i < 4; ++i) {
        int k = k0 + ty + i * 8, n = n0 + tx;
        t[ty + i * 8][tx] = (k < 600 && n < HIDDEN) ? W1[(size_t)k * HIDDEN + n] : 0.f;
    }
    __syncthreads();
    #pragma unroll
    for (int i = 0; i < 4; ++i) {
        int n = n0 + ty + i * 8, k = k0 + tx;
        Bt[(size_t)n * KPAD + k] = f2bf(t[tx][ty + i * 8]);
    }
}

// ---------------------------------------------------------------------------
// pool: gather + masked avg/max -> rep bf16 [B][640].
// One block (128 thr) per row; lanes 0..74 each own a float4 (4 dims).
// ---------------------------------------------------------------------------
__global__ __launch_bounds__(128) void pool_kernel(
    const int* __restrict__ x, const int* __restrict__ lengths,
    const float* __restrict__ emb, unsigned short* __restrict__ rep)
{
    const int b = blockIdx.x;
    const int t = threadIdx.x;

    __shared__ int sidx[MAX_LEN];
    sidx[t] = x[b * MAX_LEN + t];
    __syncthreads();

    unsigned short* rb = rep + (size_t)b * KPAD;

    if (t >= 75) {
        if (t < 85) {                      // zero pad cols 600..639
            ushort4 z = {0, 0, 0, 0};
            *(ushort4*)(rb + 600 + (t - 75) * 4) = z;
        }
        return;
    }

    int L = lengths[b];
    L = max(1, min(L, MAX_LEN));

    const int d = t * 4;
    float4 s  = {0.f, 0.f, 0.f, 0.f};
    float4 mx = {-FLT_MAX, -FLT_MAX, -FLT_MAX, -FLT_MAX};

    for (int i = 0; i < L; ++i) {
        int idx = sidx[i];
        idx = max(0, min(idx, VOCAB_SZ - 1));
        const float4 v = *(const float4*)(emb + (size_t)idx * EMB_DIM + d);
        s.x += v.x; s.y += v.y; s.z += v.z; s.w += v.w;
        mx.x = fmaxf(mx.x, v.x); mx.y = fmaxf(mx.y, v.y);
        mx.z = fmaxf(mx.z, v.z); mx.w = fmaxf(mx.w, v.w);
    }

    const float inv = 1.0f / (float)L;
    ushort4 av, mv;
    av.x = f2bf(s.x * inv); av.y = f2bf(s.y * inv);
    av.z = f2bf(s.z * inv); av.w = f2bf(s.w * inv);
    mv.x = f2bf(mx.x); mv.y = f2bf(mx.y); mv.z = f2bf(mx.z); mv.w = f2bf(mx.w);
    *(ushort4*)(rb + d)       = av;     // avg -> [0,300)
    *(ushort4*)(rb + 300 + d) = mv;     // max -> [300,600)
}

// ---------------------------------------------------------------------------
// gemm1: hidden = relu(rep @ W1 + b1) via bf16 MFMA 16x16x32.
// 64x64 tile, BK=32, 1024 blocks -> 4 blocks/CU (TLP hides load latency).
// 4 waves (2x2), wave tile 32x32 = 2x2 MFMAs. LDS 16 KB, dbuf,
// global_load_lds(16B) staging.
// NOTE: one wave-instruction of global_load_lds covers 64 lanes x 16 B
// = 1024 B = 512 shorts. Wave base MUST be wv*512 shorts. (Round-4 bug:
// wv*1024 wrote past the buffer -> NaN.)
// ---------------------------------------------------------------------------
#define BM 64
#define BN 64
#define BK 32

__global__ __launch_bounds__(256, 4) void gemm1_mfma(
    const unsigned short* __restrict__ A,    // rep  [M][640] bf16
    const unsigned short* __restrict__ Bt,   // W1T  [1024][640] bf16
    const float* __restrict__ bias,          // b1 [1000]
    unsigned short* __restrict__ H,          // hidden [M][1000] bf16
    int M)
{
    __shared__ unsigned short As[2][BM * BK];   // 4 KB each
    __shared__ unsigned short Bs[2][BN * BK];   // 4 KB each

    const int tid  = threadIdx.x;
    const int wv   = tid >> 6;
    const int lane = tid & 63;
    const int bm   = blockIdx.y * BM;
    const int bn   = blockIdx.x * BN;
    const int wr   = (wv & 1) * 32;    // wave row offset
    const int wc   = (wv >> 1) * 32;   // wave col offset

    f32x4 acc[2][2] = {};

    auto stage = [&](int buf, int k0) {
        // A tile: 64 rows x 64 B = 256 16B-chunks; 1 chunk/thread.
        {
            int ci  = wv * 64 + lane;
            int row = ci >> 2, c = ci & 3;
            const unsigned short* g = A + (size_t)(bm + row) * KPAD + k0 + c * 8;
            unsigned short* l = &As[buf][wv * 512];    // 512 shorts = 1024 B/wave
            __builtin_amdgcn_global_load_lds(g, l, 16, 0, 0);
        }
        // B tile: same shape.
        {
            int ci  = wv * 64 + lane;
            int row = ci >> 2, c = ci & 3;
            const unsigned short* g = Bt + (size_t)(bn + row) * KPAD + k0 + c * 8;
            unsigned short* l = &Bs[buf][wv * 512];
            __builtin_amdgcn_global_load_lds(g, l, 16, 0, 0);
        }
    };

    stage(0, 0);
    int cur = 0;
    const int q = lane >> 4, r16 = lane & 15;

    #pragma unroll 1
    for (int it = 0; it < KPAD / BK; ++it) {
        __syncthreads();                       // publishes buf `cur`
        if (it + 1 < KPAD / BK) stage(cur ^ 1, (it + 1) * BK);

        bf16x8 af[2], bfr[2];
        #pragma unroll
        for (int mi = 0; mi < 2; ++mi)
            af[mi] = *(const bf16x8*)&As[cur][(wr + mi * 16 + r16) * BK + q * 8];
        #pragma unroll
        for (int nj = 0; nj < 2; ++nj)
            bfr[nj] = *(const bf16x8*)&Bs[cur][(wc + nj * 16 + r16) * BK + q * 8];
        #pragma unroll
        for (int mi = 0; mi < 2; ++mi)
            #pragma unroll
            for (int nj = 0; nj < 2; ++nj)
                acc[mi][nj] = __builtin_amdgcn_mfma_f32_16x16x32_bf16(
                    af[mi], bfr[nj], acc[mi][nj], 0, 0, 0);
        cur ^= 1;
    }

    // Epilogue. C/D layout: col = lane&15, row = (lane>>4)*4 + reg.
    #pragma unroll
    for (int nj = 0; nj < 2; ++nj) {
        int n = bn + wc + nj * 16 + r16;
        if (n >= HIDDEN) continue;
        float bv = bias[n];
        #pragma unroll
        for (int mi = 0; mi < 2; ++mi) {
            #pragma unroll
            for (int r = 0; r < 4; ++r) {
                int m = bm + wr + mi * 16 + q * 4 + r;
                float v = acc[mi][nj][r] + bv;
                H[(size_t)m * HIDDEN + n] = f2bf(fmaxf(v, 0.f));
            }
        }
    }
}

// ---------------------------------------------------------------------------
// gemm2: logits = hidden @ W2 + b2. 4 waves/block, one row per wave.
// ---------------------------------------------------------------------------
__global__ __launch_bounds__(256) void gemm2_kernel(
    const unsigned short* __restrict__ Hb,   // [B][1000] bf16
    const float* __restrict__ W2,            // [1000][5]
    const float* __restrict__ b2,            // [5]
    float* __restrict__ out)                 // [B][5]
{
    const int wv   = threadIdx.x >> 6;
    const int lane = threadIdx.x & 63;
    const int b    = blockIdx.x * 4 + wv;
    const unsigned short* hr = Hb + (size_t)b * HIDDEN;

    float acc[NCLS] = {0.f, 0.f, 0.f, 0.f, 0.f};
    #pragma unroll
    for (int c = 0; c < 2; ++c) {
        int k0 = c * 512 + lane * 8;
        if (k0 + 8 <= HIDDEN) {
            ushort8v hv = *(const ushort8v*)(hr + k0);
            #pragma unroll
            for (int j = 0; j < 8; ++j) {
                float h = bf2f(hv[j]);
                const float* w = W2 + (size_t)(k0 + j) * NCLS;
                #pragma unroll
                for (int cc = 0; cc < NCLS; ++cc) acc[cc] += h * w[cc];
            }
        }
    }
    #pragma unroll
    for (int off = 32; off > 0; off >>= 1)
        #pragma unroll
        for (int cc = 0; cc < NCLS; ++cc)
            acc[cc] += __shfl_down(acc[cc], off, 64);

    if (lane == 0) {
        #pragma unroll
        for (int cc = 0; cc < NCLS; ++cc)
            out[(size_t)b * NCLS + cc] = acc[cc] + b2[cc];
    }
}

// ---------------------------------------------------------------------------
extern "C" void kernel_launch(void* const* d_in, const int* in_sizes, int n_in,
                              void* d_out, int out_size, void* d_ws, size_t ws_size,
                              hipStream_t stream)
{
    const int*   x       = (const int*)d_in[0];
    const int*   lengths = (const int*)d_in[1];
    const float* emb     = (const float*)d_in[2];
    const float* W1      = (const float*)d_in[3];
    const float* b1      = (const float*)d_in[4];
    const float* W2      = (const float*)d_in[5];
    const float* b2      = (const float*)d_in[6];
    float*       out     = (float*)d_out;

    const int B = in_sizes[1];               // 4096

    unsigned short* rep    = (unsigned short*)d_ws;          // [B][640]
    unsigned short* w1t    = rep + (size_t)B * KPAD;         // [1024][640]
    unsigned short* hidden = w1t + (size_t)NPAD * KPAD;      // [B][1000]

    transpose_w1<<<dim3(32, 20), 256, 0, stream>>>(W1, w1t);
    pool_kernel<<<B, 128, 0, stream>>>(x, lengths, emb, rep);

    dim3 g1(NPAD / BN, B / BM);              // (16, 64) = 1024 blocks
    gemm1_mfma<<<g1, 256, 0, stream>>>(rep, w1t, b1, hidden, B);

    gemm2_kernel<<<B / 4, 256, 0, stream>>>(hidden, W2, b2, out);
}

// Round 6
// 161.276 us; speedup vs baseline: 1.4061x; 1.0362x over previous
//
#include <hip/hip_runtime.h>
#include <float.h>
#include <stdint.h>

#define EMB_DIM  300
#define MAX_LEN  128
#define HIDDEN   1000
#define NCLS     5
#define VOCAB_SZ 50000
#define KPAD     640     // 600 padded to 20*32
#define NPAD     1024    // 1000 padded to 16*64
#define EMBPAD   320     // 300 dims padded to 320 shorts = 640 B = 5 x 128 B lines

typedef float    f32x4  __attribute__((ext_vector_type(4)));
typedef __bf16   bf16x8 __attribute__((ext_vector_type(8)));
typedef unsigned short ushort8v __attribute__((ext_vector_type(8)));

__device__ __forceinline__ unsigned short f2bf(float f) {
    union { float f; uint32_t u; } v; v.f = f;
    uint32_t u = v.u;
    return (unsigned short)((u + 0x7FFFu + ((u >> 16) & 1u)) >> 16);   // RNE
}
__device__ __forceinline__ float bf2f(unsigned short h) {
    union { uint32_t u; float f; } v; v.u = ((uint32_t)h) << 16;
    return v.f;
}

// ---------------------------------------------------------------------------
// convert_emb: emb [50000][300] f32 -> embb [50000][320] bf16 (zero-padded).
// Rows become exactly 5 aligned 128B lines -> halves pool's L2-line traffic.
// ---------------------------------------------------------------------------
__global__ __launch_bounds__(256) void convert_emb(
    const float* __restrict__ emb, unsigned short* __restrict__ embb)
{
    const int i = blockIdx.x * 256 + threadIdx.x;     // chunk of 4 shorts
    const int total = VOCAB_SZ * (EMBPAD / 4);
    if (i >= total) return;
    const int v  = i / (EMBPAD / 4);
    const int ch = i - v * (EMBPAD / 4);
    ushort4 o = {0, 0, 0, 0};
    if (ch < 75) {
        const float4 f = *(const float4*)(emb + (size_t)v * EMB_DIM + ch * 4);
        o.x = f2bf(f.x); o.y = f2bf(f.y); o.z = f2bf(f.z); o.w = f2bf(f.w);
    }
    *(ushort4*)(embb + (size_t)v * EMBPAD + ch * 4) = o;
}

// ---------------------------------------------------------------------------
// transpose+convert W1 [600][1000] f32 -> W1T [1024][640] bf16 (zero-padded)
// ---------------------------------------------------------------------------
__global__ __launch_bounds__(256) void transpose_w1(
    const float* __restrict__ W1, unsigned short* __restrict__ Bt)
{
    __shared__ float t[32][33];
    const int tx = threadIdx.x & 31, ty = threadIdx.x >> 5;   // 32 x 8
    const int n0 = blockIdx.x * 32, k0 = blockIdx.y * 32;
    #pragma unroll
    for (int i = 0; i < 4; ++i) {
        int k = k0 + ty + i * 8, n = n0 + tx;
        t[ty + i * 8][tx] = (k < 600 && n < HIDDEN) ? W1[(size_t)k * HIDDEN + n] : 0.f;
    }
    __syncthreads();
    #pragma unroll
    for (int i = 0; i < 4; ++i) {
        int n = n0 + ty + i * 8, k = k0 + tx;
        Bt[(size_t)n * KPAD + k] = f2bf(t[tx][ty + i * 8]);
    }
}

// ---------------------------------------------------------------------------
// transpose_w2: W2 [1000][5] f32 -> W2T [5][1024] bf16 (zero-padded)
// ---------------------------------------------------------------------------
__global__ __launch_bounds__(256) void transpose_w2(
    const float* __restrict__ W2, unsigned short* __restrict__ W2t)
{
    const int i = blockIdx.x * 256 + threadIdx.x;
    if (i >= NCLS * 1024) return;
    const int c = i >> 10, k = i & 1023;
    const float v = (k < HIDDEN) ? W2[(size_t)k * NCLS + c] : 0.f;
    W2t[(size_t)c * 1024 + k] = f2bf(v);
}

// ---------------------------------------------------------------------------
// pool_bf16: gather + masked avg/max over bf16 table -> rep bf16 [B][640].
// One block (128 thr) per row; lanes 0..74 own a ushort4 (4 dims); token
// loop unrolled x2 (2 independent row loads in flight).
// ---------------------------------------------------------------------------
__global__ __launch_bounds__(128) void pool_bf16(
    const int* __restrict__ x, const int* __restrict__ lengths,
    const unsigned short* __restrict__ embb, unsigned short* __restrict__ rep)
{
    const int b = blockIdx.x;
    const int t = threadIdx.x;

    __shared__ int sidx[MAX_LEN];
    sidx[t] = x[b * MAX_LEN + t];
    __syncthreads();

    unsigned short* rb = rep + (size_t)b * KPAD;

    if (t >= 75) {
        if (t < 85) {                      // zero pad cols 600..639
            ushort4 z = {0, 0, 0, 0};
            *(ushort4*)(rb + 600 + (t - 75) * 4) = z;
        }
        return;
    }

    int L = lengths[b];
    L = max(1, min(L, MAX_LEN));

    const int d = t * 4;
    float4 s  = {0.f, 0.f, 0.f, 0.f};
    float4 mx = {-FLT_MAX, -FLT_MAX, -FLT_MAX, -FLT_MAX};

    int i = 0;
    for (; i + 2 <= L; i += 2) {
        int i0 = max(0, min(sidx[i],     VOCAB_SZ - 1));
        int i1 = max(0, min(sidx[i + 1], VOCAB_SZ - 1));
        const ushort4 a = *(const ushort4*)(embb + (size_t)i0 * EMBPAD + d);
        const ushort4 c = *(const ushort4*)(embb + (size_t)i1 * EMBPAD + d);
        float a0 = bf2f(a.x), a1 = bf2f(a.y), a2 = bf2f(a.z), a3 = bf2f(a.w);
        float c0 = bf2f(c.x), c1 = bf2f(c.y), c2 = bf2f(c.z), c3 = bf2f(c.w);
        s.x += a0 + c0; s.y += a1 + c1; s.z += a2 + c2; s.w += a3 + c3;
        mx.x = fmaxf(mx.x, fmaxf(a0, c0)); mx.y = fmaxf(mx.y, fmaxf(a1, c1));
        mx.z = fmaxf(mx.z, fmaxf(a2, c2)); mx.w = fmaxf(mx.w, fmaxf(a3, c3));
    }
    if (i < L) {
        int i0 = max(0, min(sidx[i], VOCAB_SZ - 1));
        const ushort4 a = *(const ushort4*)(embb + (size_t)i0 * EMBPAD + d);
        float a0 = bf2f(a.x), a1 = bf2f(a.y), a2 = bf2f(a.z), a3 = bf2f(a.w);
        s.x += a0; s.y += a1; s.z += a2; s.w += a3;
        mx.x = fmaxf(mx.x, a0); mx.y = fmaxf(mx.y, a1);
        mx.z = fmaxf(mx.z, a2); mx.w = fmaxf(mx.w, a3);
    }

    const float inv = 1.0f / (float)L;
    ushort4 av, mv;
    av.x = f2bf(s.x * inv); av.y = f2bf(s.y * inv);
    av.z = f2bf(s.z * inv); av.w = f2bf(s.w * inv);
    mv.x = f2bf(mx.x); mv.y = f2bf(mx.y); mv.z = f2bf(mx.z); mv.w = f2bf(mx.w);
    *(ushort4*)(rb + d)       = av;     // avg -> [0,300)
    *(ushort4*)(rb + 300 + d) = mv;     // max -> [300,600)
}

// ---------------------------------------------------------------------------
// pool_f32 (fallback if ws too small for the bf16 table): round-5 version.
// ---------------------------------------------------------------------------
__global__ __launch_bounds__(128) void pool_f32(
    const int* __restrict__ x, const int* __restrict__ lengths,
    const float* __restrict__ emb, unsigned short* __restrict__ rep)
{
    const int b = blockIdx.x;
    const int t = threadIdx.x;

    __shared__ int sidx[MAX_LEN];
    sidx[t] = x[b * MAX_LEN + t];
    __syncthreads();

    unsigned short* rb = rep + (size_t)b * KPAD;

    if (t >= 75) {
        if (t < 85) {
            ushort4 z = {0, 0, 0, 0};
            *(ushort4*)(rb + 600 + (t - 75) * 4) = z;
        }
        return;
    }

    int L = lengths[b];
    L = max(1, min(L, MAX_LEN));

    const int d = t * 4;
    float4 s  = {0.f, 0.f, 0.f, 0.f};
    float4 mx = {-FLT_MAX, -FLT_MAX, -FLT_MAX, -FLT_MAX};

    for (int i = 0; i < L; ++i) {
        int idx = max(0, min(sidx[i], VOCAB_SZ - 1));
        const float4 v = *(const float4*)(emb + (size_t)idx * EMB_DIM + d);
        s.x += v.x; s.y += v.y; s.z += v.z; s.w += v.w;
        mx.x = fmaxf(mx.x, v.x); mx.y = fmaxf(mx.y, v.y);
        mx.z = fmaxf(mx.z, v.z); mx.w = fmaxf(mx.w, v.w);
    }

    const float inv = 1.0f / (float)L;
    ushort4 av, mv;
    av.x = f2bf(s.x * inv); av.y = f2bf(s.y * inv);
    av.z = f2bf(s.z * inv); av.w = f2bf(s.w * inv);
    mv.x = f2bf(mx.x); mv.y = f2bf(mx.y); mv.z = f2bf(mx.z); mv.w = f2bf(mx.w);
    *(ushort4*)(rb + d)       = av;
    *(ushort4*)(rb + 300 + d) = mv;
}

// ---------------------------------------------------------------------------
// gemm1: hidden = relu(rep @ W1 + b1) via bf16 MFMA 16x16x32.
// 64x64 tile, BK=32, 1024 blocks -> 4 blocks/CU. 4 waves (2x2), wave tile
// 32x32. LDS 16 KB dbuf, global_load_lds(16B) staging (wave base wv*512).
// ---------------------------------------------------------------------------
#define BM 64
#define BN 64
#define BK 32

__global__ __launch_bounds__(256, 4) void gemm1_mfma(
    const unsigned short* __restrict__ A,    // rep  [M][640] bf16
    const unsigned short* __restrict__ Bt,   // W1T  [1024][640] bf16
    const float* __restrict__ bias,          // b1 [1000]
    unsigned short* __restrict__ H,          // hidden [M][1000] bf16
    int M)
{
    __shared__ unsigned short As[2][BM * BK];
    __shared__ unsigned short Bs[2][BN * BK];

    const int tid  = threadIdx.x;
    const int wv   = tid >> 6;
    const int lane = tid & 63;
    const int bm   = blockIdx.y * BM;
    const int bn   = blockIdx.x * BN;
    const int wr   = (wv & 1) * 32;
    const int wc   = (wv >> 1) * 32;

    f32x4 acc[2][2] = {};

    auto stage = [&](int buf, int k0) {
        {
            int ci  = wv * 64 + lane;
            int row = ci >> 2, c = ci & 3;
            const unsigned short* g = A + (size_t)(bm + row) * KPAD + k0 + c * 8;
            unsigned short* l = &As[buf][wv * 512];    // 512 shorts = 1024 B/wave
            __builtin_amdgcn_global_load_lds(g, l, 16, 0, 0);
        }
        {
            int ci  = wv * 64 + lane;
            int row = ci >> 2, c = ci & 3;
            const unsigned short* g = Bt + (size_t)(bn + row) * KPAD + k0 + c * 8;
            unsigned short* l = &Bs[buf][wv * 512];
            __builtin_amdgcn_global_load_lds(g, l, 16, 0, 0);
        }
    };

    stage(0, 0);
    int cur = 0;
    const int q = lane >> 4, r16 = lane & 15;

    #pragma unroll 1
    for (int it = 0; it < KPAD / BK; ++it) {
        __syncthreads();
        if (it + 1 < KPAD / BK) stage(cur ^ 1, (it + 1) * BK);

        bf16x8 af[2], bfr[2];
        #pragma unroll
        for (int mi = 0; mi < 2; ++mi)
            af[mi] = *(const bf16x8*)&As[cur][(wr + mi * 16 + r16) * BK + q * 8];
        #pragma unroll
        for (int nj = 0; nj < 2; ++nj)
            bfr[nj] = *(const bf16x8*)&Bs[cur][(wc + nj * 16 + r16) * BK + q * 8];
        #pragma unroll
        for (int mi = 0; mi < 2; ++mi)
            #pragma unroll
            for (int nj = 0; nj < 2; ++nj)
                acc[mi][nj] = __builtin_amdgcn_mfma_f32_16x16x32_bf16(
                    af[mi], bfr[nj], acc[mi][nj], 0, 0, 0);
        cur ^= 1;
    }

    #pragma unroll
    for (int nj = 0; nj < 2; ++nj) {
        int n = bn + wc + nj * 16 + r16;
        if (n >= HIDDEN) continue;
        float bv = bias[n];
        #pragma unroll
        for (int mi = 0; mi < 2; ++mi) {
            #pragma unroll
            for (int r = 0; r < 4; ++r) {
                int m = bm + wr + mi * 16 + q * 4 + r;
                float v = acc[mi][nj][r] + bv;
                H[(size_t)m * HIDDEN + n] = f2bf(fmaxf(v, 0.f));
            }
        }
    }
}

// ---------------------------------------------------------------------------
// gemm2: logits = hidden @ W2T + b2. 4 waves/block, one row per wave.
// All loads are coalesced 16B bf16 vectors.
// ---------------------------------------------------------------------------
__global__ __launch_bounds__(256) void gemm2_kernel(
    const unsigned short* __restrict__ Hb,    // [B][1000] bf16
    const unsigned short* __restrict__ W2t,   // [5][1024] bf16
    const float* __restrict__ b2,             // [5]
    float* __restrict__ out)                  // [B][5]
{
    const int wv   = threadIdx.x >> 6;
    const int lane = threadIdx.x & 63;
    const int b    = blockIdx.x * 4 + wv;
    const unsigned short* hr = Hb + (size_t)b * HIDDEN;

    float acc[NCLS] = {0.f, 0.f, 0.f, 0.f, 0.f};
    #pragma unroll
    for (int c = 0; c < 2; ++c) {
        int k0 = c * 512 + lane * 8;
        if (k0 + 8 <= HIDDEN) {
            ushort8v hv = *(const ushort8v*)(hr + k0);
            ushort8v wv8[NCLS];
            #pragma unroll
            for (int cc = 0; cc < NCLS; ++cc)
                wv8[cc] = *(const ushort8v*)(W2t + cc * 1024 + k0);
            #pragma unroll
            for (int j = 0; j < 8; ++j) {
                float h = bf2f(hv[j]);
                #pragma unroll
                for (int cc = 0; cc < NCLS; ++cc)
                    acc[cc] += h * bf2f(wv8[cc][j]);
            }
        }
    }
    #pragma unroll
    for (int off = 32; off > 0; off >>= 1)
        #pragma unroll
        for (int cc = 0; cc < NCLS; ++cc)
            acc[cc] += __shfl_down(acc[cc], off, 64);

    if (lane == 0) {
        #pragma unroll
        for (int cc = 0; cc < NCLS; ++cc)
            out[(size_t)b * NCLS + cc] = acc[cc] + b2[cc];
    }
}

// ---------------------------------------------------------------------------
extern "C" void kernel_launch(void* const* d_in, const int* in_sizes, int n_in,
                              void* d_out, int out_size, void* d_ws, size_t ws_size,
                              hipStream_t stream)
{
    const int*   x       = (const int*)d_in[0];
    const int*   lengths = (const int*)d_in[1];
    const float* emb     = (const float*)d_in[2];
    const float* W1      = (const float*)d_in[3];
    const float* b1      = (const float*)d_in[4];
    const float* W2      = (const float*)d_in[5];
    const float* b2      = (const float*)d_in[6];
    float*       out     = (float*)d_out;

    const int B = in_sizes[1];               // 4096

    unsigned short* rep    = (unsigned short*)d_ws;           // [B][640]
    unsigned short* w1t    = rep + (size_t)B * KPAD;          // [1024][640]
    unsigned short* w2t    = w1t + (size_t)NPAD * KPAD;       // [5][1024]
    unsigned short* hidden = w2t + (size_t)NCLS * 1024;       // [B][1000]
    unsigned short* embb   = hidden + (size_t)B * HIDDEN;     // [50000][320]

    const size_t need = ((size_t)B * KPAD + (size_t)NPAD * KPAD + NCLS * 1024
                         + (size_t)B * HIDDEN + (size_t)VOCAB_SZ * EMBPAD) * 2;

    transpose_w1<<<dim3(32, 20), 256, 0, stream>>>(W1, w1t);
    transpose_w2<<<(NCLS * 1024 + 255) / 256, 256, 0, stream>>>(W2, w2t);

    if (ws_size >= need) {
        const int total = VOCAB_SZ * (EMBPAD / 4);
        convert_emb<<<(total + 255) / 256, 256, 0, stream>>>(emb, embb);
        pool_bf16<<<B, 128, 0, stream>>>(x, lengths, embb, rep);
    } else {
        pool_f32<<<B, 128, 0, stream>>>(x, lengths, emb, rep);
    }

    dim3 g1(NPAD / BN, B / BM);              // (16, 64) = 1024 blocks
    gemm1_mfma<<<g1, 256, 0, stream>>>(rep, w1t, b1, hidden, B);

    gemm2_kernel<<<B / 4, 256, 0, stream>>>(hidden, w2t, b2, out);
}